// Round 3
// baseline (202.495 us; speedup 1.0000x reference)
//
#include <hip/hip_runtime.h>
#include <math.h>

// Problem constants (fixed by setup_inputs): h [B=16, S=4096, D=512] fp32.
constexpr int B_ = 16;
constexpr int S_ = 4096;
constexpr int D_ = 512;
constexpr float MARGIN = 0.5f;
constexpr float EPS = 1e-8f;

constexpr int TGR  = 64;                // owned t's per strip (halo 19 rows
                                        // amortized: 83/64 = 1.30x bytes)
constexpr int SPB  = S_ / TGR;          // 64 strips per batch
constexpr int NSTR = B_ * SPB;          // 1024 strips
constexpr int WPB  = 4;                 // waves per block (2 strips x 2 K-halves)
constexpr int NBLK = NSTR * 2 / WPB;    // 512 blocks (2 per CU, 2 waves/SIMD)
constexpr int NW   = NSTR;              // one partial per strip

typedef __attribute__((ext_vector_type(8))) short short8;   // 8 bf16 (4 VGPRs)
typedef __attribute__((ext_vector_type(4))) float floatx4;  // MFMA 16x16 acc

// v_add_f32_dpp step: x += dpp_move(x); bound_ctrl zero-fills invalid lanes.
template <int CTRL>
__device__ __forceinline__ float dpp_add(float x) {
    int m = __builtin_amdgcn_update_dpp(0, __float_as_int(x), CTRL, 0xf, 0xf, true);
    return x + __int_as_float(m);
}
// Full wave64 sum via DPP (pure VALU). Result valid in lane 63.
__device__ __forceinline__ float wave_sum63(float x) {
    x = dpp_add<0x111>(x);  // row_shr:1
    x = dpp_add<0x112>(x);  // row_shr:2
    x = dpp_add<0x114>(x);  // row_shr:4
    x = dpp_add<0x118>(x);  // row_shr:8
    x = dpp_add<0x142>(x);  // row_bcast:15
    x = dpp_add<0x143>(x);  // row_bcast:31
    return x;
}

// Pack two fp32 into two bf16 by truncation (proven exact enough in R4-R6).
// v_perm_b32 byte-select: dst = {hi.b3, hi.b2, lo.b3, lo.b2} — 1 VALU op.
__device__ __forceinline__ unsigned int pk(float lo, float hi) {
    return __builtin_amdgcn_perm(__float_as_uint(hi), __float_as_uint(lo), 0x07060302u);
}

// R2 lesson: TGR=64 single-wave strips (1 wave/SIMD) LOST 3 us despite -20%
// bytes — latency exposure at 1 wave/SIMD masks the byte saving. This round
// keeps TGR=64's 1.30x byte amplification but K-SPLITS each strip across two
// waves (D-halves [0,256) / [256,512)), restoring 2048 waves = 2 waves/SIMD,
// the regime where R0/R1 proved time ~ bytes requested.
//
// Per strip: 12 sim tiles + 2 diag-only Gram jobs per K-step:
//   sim (A,B): (0,0)(0,1)(0,2) (1,1)(1,2)(1,3) (2,2)(2,3)(2,4) (3,3)(3,4)(3,5)
//   diag-only: f4xf4, f5xf5   (halo norms; owned diags come from AiBi)
// Coverage: A_i needs cols 16i+1 .. 16i+34 -> exactly B-blocks i,i+1,i+2;
// tiles disjoint -> the generic k-filter gives exact coverage, no dup.
// Each wave accumulates its K-half; odd wave dumps 56 floats to LDS, even
// wave adds and runs the (cheap) epilogue.
__global__ __launch_bounds__(256, 2) void tcl_partial(const float* __restrict__ h,
                                                      float* __restrict__ ws) {
    __shared__ float nlds[2][96];
    __shared__ float red[2][64][57];  // 57-pad: lane stride 25 mod 32 -> 2-way (free)

    const int tid  = threadIdx.x;
    const int lane = tid & 63;
    const int w    = tid >> 6;
    const int sw   = w >> 1;   // strip-within-block (0/1)
    const int kh   = w & 1;    // K-half

    // XCD swizzle: consecutive strips (halo-sharing neighbors) land on the
    // same XCD. Bijective for 512 blocks over 8 XCDs.
    const int p  = blockIdx.x;
    const int L  = (p & 7) * (NBLK / 8) + (p >> 3);
    const int strip = L * 2 + sw;          // 0..1023
    const int b  = strip >> 6;             // /SPB
    const int t0 = (strip & (SPB - 1)) * TGR;

    const int m16 = lane & 15;
    const int q   = lane >> 4;
    const int col0 = kh * 256 + q * 8;     // this wave's K-half, lane's chunk

    // Frag-set base pointers. B5 tail rows t0+83.. are only touched at k>19
    // (value-side filtered) -> clamp to t0+82: lanes m16>=3 broadcast-read one
    // row instead of 13 distinct HBM rows. Batch-end rows clamp to S-1 (their
    // values are excluded by the t0+gcol<S guard; strips never cross batches).
    const float* fb[6];
#pragma unroll
    for (int o = 0; o < 6; ++o) {
        int t = t0 + o * 16 + m16;
        if (o == 5 && t > t0 + 82) t = t0 + 82;  // tail rows unused (k>19)
        if (t > S_ - 1) t = S_ - 1;
        fb[o] = h + ((size_t)b * S_ + t) * D_ + col0;
    }

    floatx4 acc[14];
#pragma unroll
    for (int j = 0; j < 14; ++j) acc[j] = (floatx4){0.f, 0.f, 0.f, 0.f};

#pragma unroll
    for (int kk = 0; kk < 8; ++kk) {   // 8 K-steps of 32 over this 256-half
        short8 f[6];
#pragma unroll
        for (int o = 0; o < 6; ++o) {
            float4 x = *(const float4*)(fb[o] + kk * 32);
            float4 y = *(const float4*)(fb[o] + kk * 32 + 4);
            union { uint4 u4; short8 s8; } cv;
            cv.u4.x = pk(x.x, x.y);
            cv.u4.y = pk(x.z, x.w);
            cv.u4.z = pk(y.x, y.y);
            cv.u4.w = pk(y.z, y.w);
            f[o] = cv.s8;
        }
        acc[0]  = __builtin_amdgcn_mfma_f32_16x16x32_bf16(f[0], f[0], acc[0],  0, 0, 0);
        acc[1]  = __builtin_amdgcn_mfma_f32_16x16x32_bf16(f[0], f[1], acc[1],  0, 0, 0);
        acc[2]  = __builtin_amdgcn_mfma_f32_16x16x32_bf16(f[0], f[2], acc[2],  0, 0, 0);
        acc[3]  = __builtin_amdgcn_mfma_f32_16x16x32_bf16(f[1], f[1], acc[3],  0, 0, 0);
        acc[4]  = __builtin_amdgcn_mfma_f32_16x16x32_bf16(f[1], f[2], acc[4],  0, 0, 0);
        acc[5]  = __builtin_amdgcn_mfma_f32_16x16x32_bf16(f[1], f[3], acc[5],  0, 0, 0);
        acc[6]  = __builtin_amdgcn_mfma_f32_16x16x32_bf16(f[2], f[2], acc[6],  0, 0, 0);
        acc[7]  = __builtin_amdgcn_mfma_f32_16x16x32_bf16(f[2], f[3], acc[7],  0, 0, 0);
        acc[8]  = __builtin_amdgcn_mfma_f32_16x16x32_bf16(f[2], f[4], acc[8],  0, 0, 0);
        acc[9]  = __builtin_amdgcn_mfma_f32_16x16x32_bf16(f[3], f[3], acc[9],  0, 0, 0);
        acc[10] = __builtin_amdgcn_mfma_f32_16x16x32_bf16(f[3], f[4], acc[10], 0, 0, 0);
        acc[11] = __builtin_amdgcn_mfma_f32_16x16x32_bf16(f[3], f[5], acc[11], 0, 0, 0);
        acc[12] = __builtin_amdgcn_mfma_f32_16x16x32_bf16(f[4], f[4], acc[12], 0, 0, 0);
        acc[13] = __builtin_amdgcn_mfma_f32_16x16x32_bf16(f[5], f[5], acc[13], 0, 0, 0);
    }

    // Cross-wave partial-Gram reduction: odd K-half dumps, even K-half adds.
    if (kh == 1) {
#pragma unroll
        for (int j = 0; j < 14; ++j)
#pragma unroll
            for (int r = 0; r < 4; ++r) red[sw][lane][j * 4 + r] = acc[j][r];
    }
    __syncthreads();
    if (kh == 0) {
#pragma unroll
        for (int j = 0; j < 14; ++j)
#pragma unroll
            for (int r = 0; r < 4; ++r) acc[j][r] += red[sw][lane][j * 4 + r];

        // Diag -> per-strip norms (C/D layout: col=lane&15, row=q*4+r; diag
        // lane has q*4+r == m16, each col written exactly once). Norms for
        // clamped rows are garbage but never read (k-filter caps gcol<=82;
        // batch-end guarded by t0+gcol<S).
        const int DJ[6] = {0, 3, 6, 9, 12, 13};
        const int DB[6] = {0, 16, 32, 48, 64, 80};
#pragma unroll
        for (int d = 0; d < 6; ++d) {
#pragma unroll
            for (int r = 0; r < 4; ++r)
                if (q * 4 + r == m16) nlds[sw][DB[d] + m16] = sqrtf(acc[DJ[d]][r]);
        }
    }
    __syncthreads();  // nlds visibility (conservative; reader == writer wave)

    if (kh == 0) {
        // Sim terms. Tiles partition (grow,gcol) space (disjoint A/B pairs),
        // so the generic k-filter gives exact coverage with no double count.
        const float w1 = 1.0f / ((float)B_ * (float)(S_ - 1));
        const float w2 = 1.0f / ((float)B_ * (float)(10 * S_ - 145));
        const int SA[12] = {0, 0, 0, 16, 16, 16, 32, 32, 32, 48, 48, 48};
        const int SB[12] = {0, 16, 32, 16, 32, 48, 32, 48, 64, 48, 64, 80};
        float local = 0.f;
#pragma unroll
        for (int s2 = 0; s2 < 12; ++s2) {
            const int gcol = SB[s2] + m16;
            if (t0 + gcol < S_) {
                const float nb = nlds[sw][gcol];
#pragma unroll
                for (int r = 0; r < 4; ++r) {
                    const int grow = SA[s2] + q * 4 + r;
                    const int k = gcol - grow;
                    if (k == 1 || (k >= 10 && k <= 19)) {
                        const float sim = acc[s2][r] / fmaxf(nlds[sw][grow] * nb, EPS);
                        local += (k == 1) ? w1 * (1.0f - sim)
                                          : w2 * fmaxf(MARGIN - sim, 0.f);
                    }
                }
            }
        }
        local = wave_sum63(local);
        if (lane == 63) ws[strip] = local;  // one slot per strip
    }
}

__global__ __launch_bounds__(1024) void tcl_final(const float* __restrict__ ws,
                                                  float* __restrict__ out) {
    float v = 0.f;
    for (int j = threadIdx.x; j < NW; j += 1024) v += ws[j];
    v = wave_sum63(v);
    __shared__ float s[16];
    if ((threadIdx.x & 63) == 63) s[threadIdx.x >> 6] = v;
    __syncthreads();
    if (threadIdx.x == 0) {
        float t = 0.f;
#pragma unroll
        for (int j = 0; j < 16; j++) t += s[j];
        out[0] = t;
    }
}

extern "C" void kernel_launch(void* const* d_in, const int* in_sizes, int n_in,
                              void* d_out, int out_size, void* d_ws, size_t ws_size,
                              hipStream_t stream) {
    const float* h = (const float*)d_in[0];
    float* out = (float*)d_out;
    float* ws = (float*)d_ws;  // NW * 4 = 4 KB
    tcl_partial<<<NBLK, 256, 0, stream>>>(h, ws);
    tcl_final<<<1, 1024, 0, stream>>>(ws, out);
}

// Round 5
// 198.096 us; speedup vs baseline: 1.0222x; 1.0222x over previous
//
#include <hip/hip_runtime.h>
#include <math.h>

// Problem constants (fixed by setup_inputs): h [B=16, S=4096, D=512] fp32.
constexpr int B_ = 16;
constexpr int S_ = 4096;
constexpr int D_ = 512;
constexpr float MARGIN = 0.5f;
constexpr float EPS = 1e-8f;

constexpr int TGR  = 64;                // owned t's per strip (halo 19 rows
                                        // amortized: 83/64 = 1.30x bytes)
constexpr int SPB  = S_ / TGR;          // 64 strips per batch
constexpr int NSTR = B_ * SPB;          // 1024 strips
constexpr int NBLK = NSTR;              // one strip per 128-thread block
constexpr int NW   = NSTR;              // one partial per strip

typedef __attribute__((ext_vector_type(8))) short short8;   // 8 bf16 (4 VGPRs)
typedef __attribute__((ext_vector_type(4))) float floatx4;  // MFMA 16x16 acc

// v_add_f32_dpp step: x += dpp_move(x); bound_ctrl zero-fills invalid lanes.
template <int CTRL>
__device__ __forceinline__ float dpp_add(float x) {
    int m = __builtin_amdgcn_update_dpp(0, __float_as_int(x), CTRL, 0xf, 0xf, true);
    return x + __int_as_float(m);
}
// Full wave64 sum via DPP (pure VALU). Result valid in lane 63.
__device__ __forceinline__ float wave_sum63(float x) {
    x = dpp_add<0x111>(x);  // row_shr:1
    x = dpp_add<0x112>(x);  // row_shr:2
    x = dpp_add<0x114>(x);  // row_shr:4
    x = dpp_add<0x118>(x);  // row_shr:8
    x = dpp_add<0x142>(x);  // row_bcast:15
    x = dpp_add<0x143>(x);  // row_bcast:31
    return x;
}

// Pack two fp32 into two bf16 by truncation (proven exact enough previously).
// v_perm_b32 byte-select: dst = {hi.b3, hi.b2, lo.b3, lo.b2} — 1 VALU op.
__device__ __forceinline__ unsigned int pk(float lo, float hi) {
    return __builtin_amdgcn_perm(__float_as_uint(hi), __float_as_uint(lo), 0x07060302u);
}

// R2 lesson: TGR=64 single-wave (1 wave/SIMD) loses to latency exposure.
// R3 lesson: TGR=64 K-split at WPB=4 with full unroll under the 256-VGPR cap
// (launch_bounds .,2) regressed ~+14us over the byte model — consistent with
// scratch spills from the fat fully-unrolled body (12 in-flight float4 + 14
// accs + cross-iteration hoisting). This round closes BOTH failure modes:
//   - block = the K-half pair itself (128 thr): 1024 blocks, 4/CU, 8 waves/CU
//     = 2 waves/SIMD (TLP restored, barrier syncs only the cooperating pair)
//   - #pragma unroll 2 caps the live set (~200 VGPR) under the 256 cap.
// (R4: identical kernel resubmitted — container infra failure, no data.)
//
// Per strip: 12 sim tiles + 2 diag-only Gram jobs per K-step:
//   sim (A,B): (0,0)(0,1)(0,2) (1,1)(1,2)(1,3) (2,2)(2,3)(2,4) (3,3)(3,4)(3,5)
//   diag-only: f4xf4, f5xf5   (halo norms; owned diags come from AiBi)
// Coverage: A_i needs cols 16i+1 .. 16i+34 -> exactly B-blocks i,i+1,i+2;
// tiles disjoint -> generic k-filter gives exact coverage, no double count.
__global__ __launch_bounds__(128, 2) void tcl_partial(const float* __restrict__ h,
                                                      float* __restrict__ ws) {
    __shared__ float nlds[96];
    __shared__ float red[64][57];  // 57-pad: stride 25 mod 32 -> 2-way (free)

    const int tid  = threadIdx.x;
    const int lane = tid & 63;
    const int kh   = tid >> 6;     // K-half (wave id within pair)

    // XCD swizzle: consecutive strips (halo-sharing neighbors) land on the
    // same XCD. Bijective for 1024 blocks over 8 XCDs.
    const int p  = blockIdx.x;
    const int strip = (p & 7) * (NBLK / 8) + (p >> 3);  // 0..1023
    const int b  = strip >> 6;             // /SPB
    const int t0 = (strip & (SPB - 1)) * TGR;

    const int m16 = lane & 15;
    const int q   = lane >> 4;
    const int col0 = kh * 256 + q * 8;     // this wave's K-half, lane's chunk

    // Frag-set base pointers. B5 tail rows t0+83.. are only touched at k>19
    // (value-side filtered) -> clamp to t0+82: lanes m16>=3 broadcast-read one
    // row instead of 13 distinct HBM rows. Batch-end rows clamp to S-1 (their
    // values are excluded by the t0+gcol<S guard; strips never cross batches).
    const float* fb[6];
#pragma unroll
    for (int o = 0; o < 6; ++o) {
        int t = t0 + o * 16 + m16;
        if (o == 5 && t > t0 + 82) t = t0 + 82;  // tail rows unused (k>19)
        if (t > S_ - 1) t = S_ - 1;
        fb[o] = h + ((size_t)b * S_ + t) * D_ + col0;
    }

    floatx4 acc[14];
#pragma unroll
    for (int j = 0; j < 14; ++j) acc[j] = (floatx4){0.f, 0.f, 0.f, 0.f};

#pragma unroll 2
    for (int kk = 0; kk < 8; ++kk) {   // 8 K-steps of 32 over this 256-half
        short8 f[6];
#pragma unroll
        for (int o = 0; o < 6; ++o) {
            float4 x = *(const float4*)(fb[o] + kk * 32);
            float4 y = *(const float4*)(fb[o] + kk * 32 + 4);
            union { uint4 u4; short8 s8; } cv;
            cv.u4.x = pk(x.x, x.y);
            cv.u4.y = pk(x.z, x.w);
            cv.u4.z = pk(y.x, y.y);
            cv.u4.w = pk(y.z, y.w);
            f[o] = cv.s8;
        }
        acc[0]  = __builtin_amdgcn_mfma_f32_16x16x32_bf16(f[0], f[0], acc[0],  0, 0, 0);
        acc[1]  = __builtin_amdgcn_mfma_f32_16x16x32_bf16(f[0], f[1], acc[1],  0, 0, 0);
        acc[2]  = __builtin_amdgcn_mfma_f32_16x16x32_bf16(f[0], f[2], acc[2],  0, 0, 0);
        acc[3]  = __builtin_amdgcn_mfma_f32_16x16x32_bf16(f[1], f[1], acc[3],  0, 0, 0);
        acc[4]  = __builtin_amdgcn_mfma_f32_16x16x32_bf16(f[1], f[2], acc[4],  0, 0, 0);
        acc[5]  = __builtin_amdgcn_mfma_f32_16x16x32_bf16(f[1], f[3], acc[5],  0, 0, 0);
        acc[6]  = __builtin_amdgcn_mfma_f32_16x16x32_bf16(f[2], f[2], acc[6],  0, 0, 0);
        acc[7]  = __builtin_amdgcn_mfma_f32_16x16x32_bf16(f[2], f[3], acc[7],  0, 0, 0);
        acc[8]  = __builtin_amdgcn_mfma_f32_16x16x32_bf16(f[2], f[4], acc[8],  0, 0, 0);
        acc[9]  = __builtin_amdgcn_mfma_f32_16x16x32_bf16(f[3], f[3], acc[9],  0, 0, 0);
        acc[10] = __builtin_amdgcn_mfma_f32_16x16x32_bf16(f[3], f[4], acc[10], 0, 0, 0);
        acc[11] = __builtin_amdgcn_mfma_f32_16x16x32_bf16(f[3], f[5], acc[11], 0, 0, 0);
        acc[12] = __builtin_amdgcn_mfma_f32_16x16x32_bf16(f[4], f[4], acc[12], 0, 0, 0);
        acc[13] = __builtin_amdgcn_mfma_f32_16x16x32_bf16(f[5], f[5], acc[13], 0, 0, 0);
    }

    // Cross-wave partial-Gram reduction: odd K-half dumps, even K-half adds.
    if (kh == 1) {
#pragma unroll
        for (int j = 0; j < 14; ++j)
#pragma unroll
            for (int r = 0; r < 4; ++r) red[lane][j * 4 + r] = acc[j][r];
    }
    __syncthreads();
    if (kh == 0) {
#pragma unroll
        for (int j = 0; j < 14; ++j)
#pragma unroll
            for (int r = 0; r < 4; ++r) acc[j][r] += red[lane][j * 4 + r];

        // Diag -> per-strip norms (C/D layout: col=lane&15, row=q*4+r; diag
        // lane has q*4+r == m16, each col written exactly once). Norms for
        // clamped rows are garbage but never read (k-filter caps gcol<=82;
        // batch-end guarded by t0+gcol<S).
        const int DJ[6] = {0, 3, 6, 9, 12, 13};
        const int DB[6] = {0, 16, 32, 48, 64, 80};
#pragma unroll
        for (int d = 0; d < 6; ++d) {
#pragma unroll
            for (int r = 0; r < 4; ++r)
                if (q * 4 + r == m16) nlds[DB[d] + m16] = sqrtf(acc[DJ[d]][r]);
        }
    }
    __syncthreads();  // nlds visibility (conservative; reader == writer wave)

    if (kh == 0) {
        // Sim terms. Tiles partition (grow,gcol) space (disjoint A/B pairs),
        // so the generic k-filter gives exact coverage with no double count.
        const float w1 = 1.0f / ((float)B_ * (float)(S_ - 1));
        const float w2 = 1.0f / ((float)B_ * (float)(10 * S_ - 145));
        const int SA[12] = {0, 0, 0, 16, 16, 16, 32, 32, 32, 48, 48, 48};
        const int SB[12] = {0, 16, 32, 16, 32, 48, 32, 48, 64, 48, 64, 80};
        float local = 0.f;
#pragma unroll
        for (int s2 = 0; s2 < 12; ++s2) {
            const int gcol = SB[s2] + m16;
            if (t0 + gcol < S_) {
                const float nb = nlds[gcol];
#pragma unroll
                for (int r = 0; r < 4; ++r) {
                    const int grow = SA[s2] + q * 4 + r;
                    const int k = gcol - grow;
                    if (k == 1 || (k >= 10 && k <= 19)) {
                        const float sim = acc[s2][r] / fmaxf(nlds[grow] * nb, EPS);
                        local += (k == 1) ? w1 * (1.0f - sim)
                                          : w2 * fmaxf(MARGIN - sim, 0.f);
                    }
                }
            }
        }
        local = wave_sum63(local);
        if (lane == 63) ws[strip] = local;  // one slot per strip
    }
}

__global__ __launch_bounds__(1024) void tcl_final(const float* __restrict__ ws,
                                                  float* __restrict__ out) {
    float v = 0.f;
    for (int j = threadIdx.x; j < NW; j += 1024) v += ws[j];
    v = wave_sum63(v);
    __shared__ float s[16];
    if ((threadIdx.x & 63) == 63) s[threadIdx.x >> 6] = v;
    __syncthreads();
    if (threadIdx.x == 0) {
        float t = 0.f;
#pragma unroll
        for (int j = 0; j < 16; j++) t += s[j];
        out[0] = t;
    }
}

extern "C" void kernel_launch(void* const* d_in, const int* in_sizes, int n_in,
                              void* d_out, int out_size, void* d_ws, size_t ws_size,
                              hipStream_t stream) {
    const float* h = (const float*)d_in[0];
    float* out = (float*)d_out;
    float* ws = (float*)d_ws;  // NW * 4 = 4 KB
    tcl_partial<<<NBLK, 128, 0, stream>>>(h, ws);
    tcl_final<<<1, 1024, 0, stream>>>(ws, out);
}

// Round 6
// 197.355 us; speedup vs baseline: 1.0260x; 1.0038x over previous
//
#include <hip/hip_runtime.h>
#include <math.h>

// Problem constants (fixed by setup_inputs): h [B=16, S=4096, D=512] fp32.
constexpr int B_ = 16;
constexpr int S_ = 4096;
constexpr int D_ = 512;
constexpr float MARGIN = 0.5f;
constexpr float EPS = 1e-8f;

constexpr int TGR  = 64;                // owned t's per strip (halo 19 rows
                                        // amortized: 83/64 = 1.30x bytes)
constexpr int SPB  = S_ / TGR;          // 64 strips per batch
constexpr int NSTR = B_ * SPB;          // 1024 strips
constexpr int NBLK = NSTR;              // one strip per 128-thread block
constexpr int NW   = NSTR;              // one partial per strip

typedef __attribute__((ext_vector_type(8))) short short8;   // 8 bf16 (4 VGPRs)
typedef __attribute__((ext_vector_type(4))) float floatx4;  // MFMA 16x16 acc

// v_add_f32_dpp step: x += dpp_move(x); bound_ctrl zero-fills invalid lanes.
template <int CTRL>
__device__ __forceinline__ float dpp_add(float x) {
    int m = __builtin_amdgcn_update_dpp(0, __float_as_int(x), CTRL, 0xf, 0xf, true);
    return x + __int_as_float(m);
}
// Full wave64 sum via DPP (pure VALU). Result valid in lane 63.
__device__ __forceinline__ float wave_sum63(float x) {
    x = dpp_add<0x111>(x);  // row_shr:1
    x = dpp_add<0x112>(x);  // row_shr:2
    x = dpp_add<0x114>(x);  // row_shr:4
    x = dpp_add<0x118>(x);  // row_shr:8
    x = dpp_add<0x142>(x);  // row_bcast:15
    x = dpp_add<0x143>(x);  // row_bcast:31
    return x;
}

// Pack two fp32 into two bf16 by truncation (proven exact enough previously).
// v_perm_b32 byte-select: dst = {hi.b3, hi.b2, lo.b3, lo.b2} — 1 VALU op.
__device__ __forceinline__ unsigned int pk(float lo, float hi) {
    return __builtin_amdgcn_perm(__float_as_uint(hi), __float_as_uint(lo), 0x07060302u);
}

// Ladder so far:
//   R2: TGR=64 1-wave (1 wave/SIMD) — latency-exposed, lost.
//   R3: TGR=64 K-split, WPB=4, full unroll under (256,2) — spills, lost.
//   R5: TGR=64 K-split pair-block (128,2), unroll 2 — parity with R1:
//       byte saving real (170 vs 214 MB) but eaten by load-latency exposure
//       (only ~12 loads outstanding/wave; per-SIMD in-flight ~0.4 KB << the
//       ~8 KB/CU needed to stream 6+ TB/s).
// R6 (this round): explicit 2-deep register double-buffer. Each kk-step's 12
// float4 loads are issued a full iteration ahead of their consume; converts
// kill the old buffer, reissue happens BEFORE the MFMAs. Outstanding depth
// 24-36 loads/wave, bounded by construction (named bufs, static indices —
// no compiler hoist blowup, no scratch). ~200 VGPR < 256 cap.
//
// Per strip: 12 sim tiles + 2 diag-only Gram jobs per K-step:
//   sim (A,B): (0,0)(0,1)(0,2) (1,1)(1,2)(1,3) (2,2)(2,3)(2,4) (3,3)(3,4)(3,5)
//   diag-only: f4xf4, f5xf5   (halo norms; owned diags come from AiBi)
// Coverage: A_i needs cols 16i+1 .. 16i+34 -> exactly B-blocks i,i+1,i+2;
// tiles disjoint -> generic k-filter gives exact coverage, no double count.

#define LOADK(X, Y, KK)                                       \
    _Pragma("unroll") for (int o = 0; o < 6; ++o) {           \
        X[o] = *(const float4*)(fb[o] + (KK) * 32);           \
        Y[o] = *(const float4*)(fb[o] + (KK) * 32 + 4);       \
    }

#define CONVERT(F, X, Y)                                      \
    _Pragma("unroll") for (int o = 0; o < 6; ++o) {           \
        union { uint4 u4; short8 s8; } cv;                    \
        cv.u4.x = pk(X[o].x, X[o].y);                         \
        cv.u4.y = pk(X[o].z, X[o].w);                         \
        cv.u4.z = pk(Y[o].x, Y[o].y);                         \
        cv.u4.w = pk(Y[o].z, Y[o].w);                         \
        F[o] = cv.s8;                                         \
    }

#define MFMA14(F)                                                                     \
    acc[0]  = __builtin_amdgcn_mfma_f32_16x16x32_bf16(F[0], F[0], acc[0],  0, 0, 0);  \
    acc[1]  = __builtin_amdgcn_mfma_f32_16x16x32_bf16(F[0], F[1], acc[1],  0, 0, 0);  \
    acc[2]  = __builtin_amdgcn_mfma_f32_16x16x32_bf16(F[0], F[2], acc[2],  0, 0, 0);  \
    acc[3]  = __builtin_amdgcn_mfma_f32_16x16x32_bf16(F[1], F[1], acc[3],  0, 0, 0);  \
    acc[4]  = __builtin_amdgcn_mfma_f32_16x16x32_bf16(F[1], F[2], acc[4],  0, 0, 0);  \
    acc[5]  = __builtin_amdgcn_mfma_f32_16x16x32_bf16(F[1], F[3], acc[5],  0, 0, 0);  \
    acc[6]  = __builtin_amdgcn_mfma_f32_16x16x32_bf16(F[2], F[2], acc[6],  0, 0, 0);  \
    acc[7]  = __builtin_amdgcn_mfma_f32_16x16x32_bf16(F[2], F[3], acc[7],  0, 0, 0);  \
    acc[8]  = __builtin_amdgcn_mfma_f32_16x16x32_bf16(F[2], F[4], acc[8],  0, 0, 0);  \
    acc[9]  = __builtin_amdgcn_mfma_f32_16x16x32_bf16(F[3], F[3], acc[9],  0, 0, 0);  \
    acc[10] = __builtin_amdgcn_mfma_f32_16x16x32_bf16(F[3], F[4], acc[10], 0, 0, 0);  \
    acc[11] = __builtin_amdgcn_mfma_f32_16x16x32_bf16(F[3], F[5], acc[11], 0, 0, 0);  \
    acc[12] = __builtin_amdgcn_mfma_f32_16x16x32_bf16(F[4], F[4], acc[12], 0, 0, 0);  \
    acc[13] = __builtin_amdgcn_mfma_f32_16x16x32_bf16(F[5], F[5], acc[13], 0, 0, 0);

__global__ __launch_bounds__(128, 2) void tcl_partial(const float* __restrict__ h,
                                                      float* __restrict__ ws) {
    __shared__ float nlds[96];
    __shared__ float red[64][57];  // 57-pad: stride 25 mod 32 -> 2-way (free)

    const int tid  = threadIdx.x;
    const int lane = tid & 63;
    const int kh   = tid >> 6;     // K-half (wave id within pair)

    // XCD swizzle: consecutive strips (halo-sharing neighbors) land on the
    // same XCD. Bijective for 1024 blocks over 8 XCDs.
    const int p  = blockIdx.x;
    const int strip = (p & 7) * (NBLK / 8) + (p >> 3);  // 0..1023
    const int b  = strip >> 6;             // /SPB
    const int t0 = (strip & (SPB - 1)) * TGR;

    const int m16 = lane & 15;
    const int q   = lane >> 4;
    const int col0 = kh * 256 + q * 8;     // this wave's K-half, lane's chunk

    // Frag-set base pointers. B5 tail rows t0+83.. are only touched at k>19
    // (value-side filtered) -> clamp to t0+82: lanes m16>=3 broadcast-read one
    // row instead of 13 distinct HBM rows. Batch-end rows clamp to S-1 (their
    // values are excluded by the t0+gcol<S guard; strips never cross batches).
    const float* fb[6];
#pragma unroll
    for (int o = 0; o < 6; ++o) {
        int t = t0 + o * 16 + m16;
        if (o == 5 && t > t0 + 82) t = t0 + 82;  // tail rows unused (k>19)
        if (t > S_ - 1) t = S_ - 1;
        fb[o] = h + ((size_t)b * S_ + t) * D_ + col0;
    }

    floatx4 acc[14];
#pragma unroll
    for (int j = 0; j < 14; ++j) acc[j] = (floatx4){0.f, 0.f, 0.f, 0.f};

    // Software-pipelined main loop: 8 K-steps of 32 over this 256-half,
    // 2-deep register double-buffer (ax/ay <- even kk, bx/by <- odd kk).
    {
        float4 ax[6], ay[6], bx[6], by[6];
        short8 f[6];
        LOADK(ax, ay, 0)
        LOADK(bx, by, 1)
#pragma unroll 1
        for (int it = 0; it < 3; ++it) {
            const int kk = 2 * it;
            CONVERT(f, ax, ay)       // waits on ax/ay; buffer dies here
            LOADK(ax, ay, kk + 2)    // reissue BEFORE the MFMAs
            MFMA14(f)
            CONVERT(f, bx, by)
            LOADK(bx, by, kk + 3)
            MFMA14(f)
        }
        CONVERT(f, ax, ay)           // kk=6
        MFMA14(f)
        CONVERT(f, bx, by)           // kk=7
        MFMA14(f)
    }

    // Cross-wave partial-Gram reduction: odd K-half dumps, even K-half adds.
    if (kh == 1) {
#pragma unroll
        for (int j = 0; j < 14; ++j)
#pragma unroll
            for (int r = 0; r < 4; ++r) red[lane][j * 4 + r] = acc[j][r];
    }
    __syncthreads();
    if (kh == 0) {
#pragma unroll
        for (int j = 0; j < 14; ++j)
#pragma unroll
            for (int r = 0; r < 4; ++r) acc[j][r] += red[lane][j * 4 + r];

        // Diag -> per-strip norms (C/D layout: col=lane&15, row=q*4+r; diag
        // lane has q*4+r == m16, each col written exactly once). Norms for
        // clamped rows are garbage but never read (k-filter caps gcol<=82;
        // batch-end guarded by t0+gcol<S).
        const int DJ[6] = {0, 3, 6, 9, 12, 13};
        const int DB[6] = {0, 16, 32, 48, 64, 80};
#pragma unroll
        for (int d = 0; d < 6; ++d) {
#pragma unroll
            for (int r = 0; r < 4; ++r)
                if (q * 4 + r == m16) nlds[DB[d] + m16] = sqrtf(acc[DJ[d]][r]);
        }
    }
    __syncthreads();  // nlds visibility (conservative; reader == writer wave)

    if (kh == 0) {
        // Sim terms. Tiles partition (grow,gcol) space (disjoint A/B pairs),
        // so the generic k-filter gives exact coverage with no double count.
        const float w1 = 1.0f / ((float)B_ * (float)(S_ - 1));
        const float w2 = 1.0f / ((float)B_ * (float)(10 * S_ - 145));
        const int SA[12] = {0, 0, 0, 16, 16, 16, 32, 32, 32, 48, 48, 48};
        const int SB[12] = {0, 16, 32, 16, 32, 48, 32, 48, 64, 48, 64, 80};
        float local = 0.f;
#pragma unroll
        for (int s2 = 0; s2 < 12; ++s2) {
            const int gcol = SB[s2] + m16;
            if (t0 + gcol < S_) {
                const float nb = nlds[gcol];
#pragma unroll
                for (int r = 0; r < 4; ++r) {
                    const int grow = SA[s2] + q * 4 + r;
                    const int k = gcol - grow;
                    if (k == 1 || (k >= 10 && k <= 19)) {
                        const float sim = acc[s2][r] / fmaxf(nlds[grow] * nb, EPS);
                        local += (k == 1) ? w1 * (1.0f - sim)
                                          : w2 * fmaxf(MARGIN - sim, 0.f);
                    }
                }
            }
        }
        local = wave_sum63(local);
        if (lane == 63) ws[strip] = local;  // one slot per strip
    }
}

__global__ __launch_bounds__(1024) void tcl_final(const float* __restrict__ ws,
                                                  float* __restrict__ out) {
    float v = 0.f;
    for (int j = threadIdx.x; j < NW; j += 1024) v += ws[j];
    v = wave_sum63(v);
    __shared__ float s[16];
    if ((threadIdx.x & 63) == 63) s[threadIdx.x >> 6] = v;
    __syncthreads();
    if (threadIdx.x == 0) {
        float t = 0.f;
#pragma unroll
        for (int j = 0; j < 16; j++) t += s[j];
        out[0] = t;
    }
}

extern "C" void kernel_launch(void* const* d_in, const int* in_sizes, int n_in,
                              void* d_out, int out_size, void* d_ws, size_t ws_size,
                              hipStream_t stream) {
    const float* h = (const float*)d_in[0];
    float* out = (float*)d_out;
    float* ws = (float*)d_ws;  // NW * 4 = 4 KB
    tcl_partial<<<NBLK, 128, 0, stream>>>(h, ws);
    tcl_final<<<1, 1024, 0, stream>>>(ws, out);
}

// Round 7
// 197.012 us; speedup vs baseline: 1.0278x; 1.0017x over previous
//
#include <hip/hip_runtime.h>
#include <math.h>

// Problem constants (fixed by setup_inputs): h [B=16, S=4096, D=512] fp32.
constexpr int B_ = 16;
constexpr int S_ = 4096;
constexpr int D_ = 512;
constexpr float MARGIN = 0.5f;
constexpr float EPS = 1e-8f;

constexpr int TGR = 32;                      // owned t's per wave
constexpr int WPB = 4;                       // waves per block
constexpr int NBLK = B_ * S_ / (TGR * WPB);  // 512 blocks (2 per CU)
constexpr int NW   = NBLK * WPB;             // 2048 waves

typedef __attribute__((ext_vector_type(8))) short short8;   // 8 bf16 (4 VGPRs)
typedef __attribute__((ext_vector_type(4))) float floatx4;  // MFMA 16x16 acc

// v_add_f32_dpp step: x += dpp_move(x); bound_ctrl zero-fills invalid lanes.
template <int CTRL>
__device__ __forceinline__ float dpp_add(float x) {
    int m = __builtin_amdgcn_update_dpp(0, __float_as_int(x), CTRL, 0xf, 0xf, true);
    return x + __int_as_float(m);
}
// Full wave64 sum via DPP (pure VALU). Result valid in lane 63.
__device__ __forceinline__ float wave_sum63(float x) {
    x = dpp_add<0x111>(x);  // row_shr:1
    x = dpp_add<0x112>(x);  // row_shr:2
    x = dpp_add<0x114>(x);  // row_shr:4
    x = dpp_add<0x118>(x);  // row_shr:8
    x = dpp_add<0x142>(x);  // row_bcast:15
    x = dpp_add<0x143>(x);  // row_bcast:31
    return x;
}

// Pack two fp32 into two bf16 by truncation (proven exact enough in R4-R6).
// v_perm_b32 byte-select: dst = {hi.b3, hi.b2, lo.b3, lo.b2} — 1 VALU op.
__device__ __forceinline__ unsigned int pk(float lo, float hi) {
    return __builtin_amdgcn_perm(__float_as_uint(hi), __float_as_uint(lo), 0x07060302u);
}

// FINAL CONFIGURATION (= R1, best measured 195.7 us).
// Session ladder: R1 195.7 | R2 198.7 (TGR=64 1-wave: latency-exposed)
// | R3 202.5 (TGR=64 K-split WPB=4: spills) | R5 198.1 (pair-block) |
// R6 197.4 (pair-block + explicit dbuf). TGR=64's 44 MB byte saving never
// converted to time across three structures -> below ~214 MB the kernel is
// floored by address-divergent VMEM issue (16 distinct cache lines per
// float4 load), not HBM BW. R1 sits within ~10% of its 34 us byte model;
// the two 77-us harness poison fills dominate the measured total.
//
// Each wave is fully self-contained: owns rows [t0, t0+32), loads 4 row-frag
// sets (row offsets 0/16/32/48) STRAIGHT from global (no LDS staging — every
// staged variant lost on occupancy/LDS-pipe/barriers), and computes 8 MFMA
// 16x16x32 Gram jobs per K-step:
//   sim tiles: (A0,B0) (A0,B1) (A0,B2) (A1,B1) (A1,B2) (A1,B3)
//   diag-only: f2xf2, f3xf3  (halo norms; owned diag comes from A0B0/A1B1)
// Norms are shared across lanes via a tiny per-wave LDS array (1 KB/block).
//
// B3 tail clamp: rows t0+51..t0+63 are only ever touched at k>19, which the
// value-side filter discards — clamp their addresses to row t0+50 so lanes
// m16>=3 broadcast-read one row instead of 13 distinct HBM rows (-17% bytes,
// -7.8 us measured R0->R1).
__global__ __launch_bounds__(256, 2) void tcl_partial(const float* __restrict__ h,
                                                      float* __restrict__ ws) {
    __shared__ float nlds[WPB][64];

    const int tid  = threadIdx.x;
    const int lane = tid & 63;
    const int w    = tid >> 6;

    // XCD swizzle: consecutive strips (halo-sharing neighbors) land on the
    // same XCD for L2 halo hits. Bijective for 512 blocks over 8 XCDs.
    const int p  = blockIdx.x;
    const int L  = (p & 7) * (NBLK / 8) + (p >> 3);
    const int gw = L * WPB + w;            // 0..2047
    const int b  = gw >> 7;                // 128 waves per batch (S/TGR)
    const int t0 = (gw & 127) * TGR;

    const int m16 = lane & 15;
    const int q   = lane >> 4;
    const int q8  = q * 8;

    // Frag-set base pointers (rows clamped to S-1; clamped cols are excluded
    // value-side by the t0+gcol<S guard / k-filter, never cross batch).
    const float* fb[4];
#pragma unroll
    for (int o = 0; o < 4; ++o) {
        int t = t0 + o * 16 + m16;
        if (o == 3 && t > t0 + 50) t = t0 + 50;  // tail rows unused (k>19)
        if (t > S_ - 1) t = S_ - 1;
        fb[o] = h + ((size_t)b * S_ + t) * D_ + q8;
    }

    floatx4 acc[8];
#pragma unroll
    for (int j = 0; j < 8; ++j) acc[j] = (floatx4){0.f, 0.f, 0.f, 0.f};

#pragma unroll
    for (int kk = 0; kk < 16; ++kk) {
        short8 f[4];
#pragma unroll
        for (int o = 0; o < 4; ++o) {
            float4 x = *(const float4*)(fb[o] + kk * 32);
            float4 y = *(const float4*)(fb[o] + kk * 32 + 4);
            union { uint4 u4; short8 s8; } cv;
            cv.u4.x = pk(x.x, x.y);
            cv.u4.y = pk(x.z, x.w);
            cv.u4.z = pk(y.x, y.y);
            cv.u4.w = pk(y.z, y.w);
            f[o] = cv.s8;
        }
        acc[0] = __builtin_amdgcn_mfma_f32_16x16x32_bf16(f[0], f[0], acc[0], 0, 0, 0);
        acc[1] = __builtin_amdgcn_mfma_f32_16x16x32_bf16(f[0], f[1], acc[1], 0, 0, 0);
        acc[2] = __builtin_amdgcn_mfma_f32_16x16x32_bf16(f[0], f[2], acc[2], 0, 0, 0);
        acc[3] = __builtin_amdgcn_mfma_f32_16x16x32_bf16(f[1], f[1], acc[3], 0, 0, 0);
        acc[4] = __builtin_amdgcn_mfma_f32_16x16x32_bf16(f[1], f[2], acc[4], 0, 0, 0);
        acc[5] = __builtin_amdgcn_mfma_f32_16x16x32_bf16(f[1], f[3], acc[5], 0, 0, 0);
        acc[6] = __builtin_amdgcn_mfma_f32_16x16x32_bf16(f[2], f[2], acc[6], 0, 0, 0);
        acc[7] = __builtin_amdgcn_mfma_f32_16x16x32_bf16(f[3], f[3], acc[7], 0, 0, 0);
    }

    // Diag -> per-wave norms (C/D layout: col=lane&15, row=q*4+r; diag lane
    // has q*4+r == m16, each col written exactly once). Norms for cols 51..63
    // are garbage (clamped rows) but never read: sim k-filter caps gcol at 50.
    const int DJ[4] = {0, 3, 6, 7};
    const int DB[4] = {0, 16, 32, 48};
#pragma unroll
    for (int d = 0; d < 4; ++d) {
#pragma unroll
        for (int r = 0; r < 4; ++r)
            if (q * 4 + r == m16) nlds[w][DB[d] + m16] = sqrtf(acc[DJ[d]][r]);
    }
    __syncthreads();  // orders intra-wave LDS write->read conservatively

    // Sim terms. Tiles partition (grow,gcol) space (disjoint A/B ranges), so
    // the generic k-filter gives exact coverage with no double count.
    const float w1 = 1.0f / ((float)B_ * (float)(S_ - 1));
    const float w2 = 1.0f / ((float)B_ * (float)(10 * S_ - 145));
    const int SA[6] = {0, 0, 0, 16, 16, 16};
    const int SB[6] = {0, 16, 32, 16, 32, 48};
    float local = 0.f;
#pragma unroll
    for (int s2 = 0; s2 < 6; ++s2) {
        const int gcol = SB[s2] + m16;
        if (t0 + gcol < S_) {
            const float nb = nlds[w][gcol];
#pragma unroll
            for (int r = 0; r < 4; ++r) {
                const int grow = SA[s2] + q * 4 + r;
                const int k = gcol - grow;
                if (k == 1 || (k >= 10 && k <= 19)) {
                    const float sim = acc[s2][r] / fmaxf(nlds[w][grow] * nb, EPS);
                    local += (k == 1) ? w1 * (1.0f - sim)
                                      : w2 * fmaxf(MARGIN - sim, 0.f);
                }
            }
        }
    }

    local = wave_sum63(local);
    if (lane == 63) ws[gw] = local;  // every wave writes its own slot
}

__global__ __launch_bounds__(1024) void tcl_final(const float* __restrict__ ws,
                                                  float* __restrict__ out) {
    float v = 0.f;
    for (int j = threadIdx.x; j < NW; j += 1024) v += ws[j];
    v = wave_sum63(v);
    __shared__ float s[16];
    if ((threadIdx.x & 63) == 63) s[threadIdx.x >> 6] = v;
    __syncthreads();
    if (threadIdx.x == 0) {
        float t = 0.f;
#pragma unroll
        for (int j = 0; j < 16; j++) t += s[j];
        out[0] = t;
    }
}

extern "C" void kernel_launch(void* const* d_in, const int* in_sizes, int n_in,
                              void* d_out, int out_size, void* d_ws, size_t ws_size,
                              hipStream_t stream) {
    const float* h = (const float*)d_in[0];
    float* out = (float*)d_out;
    float* ws = (float*)d_ws;  // NW * 4 = 8 KB
    tcl_partial<<<NBLK, 256, 0, stream>>>(h, ws);
    tcl_final<<<1, 1024, 0, stream>>>(ws, out);
}